// Round 6
// baseline (181.214 us; speedup 1.0000x reference)
//
#include <hip/hip_runtime.h>

// TV-L1 optical flow, B=4, 512x512, 20 iters — temporal blocking (ghost zones)
// R11: hoist launch-invariant statics out of k_fused. R10's prologue spent
// ~23K LDS-pipe cycles/CU (27 ds_read_b32/thread for the x1 3x3 stencil) +
// 2 extra barriers recomputing statics that never change across the 4
// launches. New tiny k_statics kernel computes (gx,gy) once per pixel into
// an 8MB float2 workspace plane; k_fused loads statics + state straight
// into registers and fills LDS in the SAME pass (x1-staging alias is gone,
// so spa needs no staging role): prologue = 1 barrier instead of 4, zero
// stencil LDS traffic. rc and nm are recomputed from x0/x1 center loads
// (+3 VALU) to keep workspace at 24+8=32MB. Main loop, epilogue, geometry
// (T=32, REG=48, TPB=768, SLOTS=3 exact-fit, 2 blocks/CU, 6 waves/SIMD)
// byte-identical to R10's proven-clean body (R6-R8 lesson: don't perturb
// the body; IR-level array demotion to scratch).
//   LDS: su=(u1,u2), spa=(p11,p21), spb=(p12,p22), 3 x 2304 x 8B = 55.3 KB.
// Halo L=6/R=10 (48x48 region per 32x32 tile). Zero-padding reproduced by
// forcing u=p=0 on out-of-image pixels (and nm=EPS there to avoid
// rcp(0)=inf NaN paths, matching the old staged-zeros semantics exactly).
// Last kernel skips the dead 20th p-update and fuses the 3x3 avgpool.

#define HH 512
#define WW 512
#define BB 4
constexpr int HW   = HH * WW;
constexpr int NTOT = BB * HW;
constexpr float EPS = 1e-8f;

#define T 32          // output tile edge
#define HALO_L 6      // left/top halo
#define REG 48        // region edge = 32 + 6 + 10
#define NPX (REG * REG)   // 2304
#define TPB 768
#define SLOTS 3       // 768*3 == 2304 exactly
#define NBLK 1024     // 4 images x 16x16 tiles

// ---- statics kernel: per-pixel image-gradient (gx,gy) of x1, once -------
__global__ __launch_bounds__(256) void k_statics(
    const float* __restrict__ x, float2* __restrict__ st)
{
    int gid = blockIdx.x * 256 + threadIdx.x;      // 0 .. NTOT-1
    int b   = gid >> 18;                           // / HW (262144)
    int l   = gid & (HW - 1);
    int i   = l >> 9, j = l & 511;
    const float* x1p = x + (size_t)b * 2 * HW + HW;
    float a00 = ((i > 0) & (j > 0))            ? x1p[l - WW - 1] : 0.f;
    float a01 = (i > 0)                        ? x1p[l - WW]     : 0.f;
    float a02 = ((i > 0) & (j < WW - 1))       ? x1p[l - WW + 1] : 0.f;
    float a10 = (j > 0)                        ? x1p[l - 1]      : 0.f;
    float a12 = (j < WW - 1)                   ? x1p[l + 1]      : 0.f;
    float a20 = ((i < HH - 1) & (j > 0))       ? x1p[l + WW - 1] : 0.f;
    float a21 = (i < HH - 1)                   ? x1p[l + WW]     : 0.f;
    float a22 = ((i < HH - 1) & (j < WW - 1))  ? x1p[l + WW + 1] : 0.f;
    const float c6 = 1.f / 6.f;
    float gx = c6 * (-a00 + a02 - 2.f * a10 + 2.f * a12 - a20 + a22);
    float gy = c6 * (-a00 - 2.f * a01 - a02 + a20 + 2.f * a21 + a22);
    st[gid] = make_float2(gx, gy);
}

// phase: 0 = first (u,p zero-init, write back), 1 = middle (load, write
// back), 2 = last (load, 5 u-phases + 4 p-phases, fused avgpool -> out).
__global__ __launch_bounds__(TPB, 1) void k_fused(
    const float* __restrict__ x,
    float2* __restrict__ ug, float4* __restrict__ pg,
    const float2* __restrict__ st,
    const float* __restrict__ lam_p, const float* __restrict__ tau_p,
    const float* __restrict__ theta_p,
    const float* __restrict__ wxp, const float* __restrict__ wyp,
    float* __restrict__ out, int phase)
{
    __shared__ float2 su[NPX];    // (u1,u2)
    __shared__ float2 spa[NPX];   // (p11,p21)
    __shared__ float2 spb[NPX];   // (p12,p22)   -> 55.3 KB total

    const int tid  = threadIdx.x;
    const int blk  = blockIdx.x;
    const int bimg = blk >> 8;
    const int t    = blk & 255;
    const int gi0  = (t >> 4) * T;
    const int gj0  = (t & 15) * T;

    const float lam = lam_p[0], theta = theta_p[0];
    const float r   = tau_p[0] / theta;
    const float tl  = theta * lam;
    const float wx0 = wxp[0], wx1 = wxp[1], wx2 = wxp[2];
    const float wy0 = wyp[0], wy1 = wyp[1], wy2 = wyp[2];

    const int gbase = bimg * HW;
    const float* x0p = x + (size_t)bimg * 2 * HW;
    const float* x1p = x0p + HW;

    int  lis[SLOTS], ljs[SLOTS], gofs[SLOTS];
    bool inb[SLOTS];
    float2 ruv[SLOTS], rpa[SLOTS], rpb[SLOTS];  // own-pixel mirrors
    float rgx[SLOTS], rgy[SLOTS], rrc[SLOTS], rth[SLOTS], rnv[SLOTS];

    // ---- single prologue pass: indices + state/statics loads + LDS fill --
    #pragma unroll
    for (int s = 0; s < SLOTS; ++s) {
        int idx = tid + s * TPB;                  // < NPX always (768*3=2304)
        int li = idx / REG, lj = idx - li * REG;
        lis[s] = li; ljs[s] = lj;
        int gi = gi0 + li - HALO_L, gj = gj0 + lj - HALO_L;
        bool in = ((unsigned)gi < HH) & ((unsigned)gj < WW);
        inb[s] = in;
        int gl = gi * WW + gj;            // valid only when in
        gofs[s] = gl;
        float2 uv = make_float2(0.f, 0.f);
        float4 p4 = make_float4(0.f, 0.f, 0.f, 0.f);
        float2 g2 = make_float2(0.f, 0.f);
        float  x0v = 0.f, x1v = 0.f;
        if (in) {
            g2  = st[gbase + gl];
            x0v = x0p[gl];
            x1v = x1p[gl];
            if (phase != 0) {
                uv = ug[gbase + gl];
                p4 = pg[gbase + gl];
            }
        }
        float nm = g2.x * g2.x + g2.y * g2.y + EPS;  // == EPS when !in
        rgx[s] = g2.x; rgy[s] = g2.y;
        rrc[s] = x1v - x0v;               // zero-padded conv semantics held
        rth[s] = tl * nm;
        rnv[s] = __builtin_amdgcn_rcpf(nm);
        ruv[s] = uv;
        rpa[s] = make_float2(p4.x, p4.y);
        rpb[s] = make_float2(p4.z, p4.w);
        su[idx]  = uv;
        spa[idx] = rpa[s];
        spb[idx] = rpb[s];
    }
    __syncthreads();

    // ---- 5 fused iterations ---------------------------------------------
    for (int k = 1; k <= 5; ++k) {
        // u-phase over li,lj in [k, REG-2k]  (valid cone of u^k)
        const int lo = k, hi_u = REG - 2 * k;
        #pragma unroll
        for (int s = 0; s < SLOTS; ++s) {
            int idx = tid + s * TPB;
            int li = lis[s], lj = ljs[s];
            if (li < lo || li > hi_u || lj < lo || lj > hi_u) continue;
            float2 uv = ruv[s];
            float rho = rrc[s] + rgx[s] * uv.x + rgy[s] * uv.y;
            // th>0 always (nm>=EPS, tl>0), so rho==0 takes the inside branch:
            // copysignf(tl,0) is never selected -> sign(0)=0 handled.
            float d = (fabsf(rho) < rth[s]) ? rho * rnv[s] : copysignf(tl, rho);
            float v1 = uv.x - d * rgx[s];
            float v2 = uv.y - d * rgy[s];
            float2 pal = spa[idx - 1],   par = spa[idx + 1];
            float2 pbt = spb[idx - REG], pbb = spb[idx + REG];
            float2 pac = rpa[s],         pbc = rpb[s];
            float div1 = wx0 * pal.x + wx1 * pac.x + wx2 * par.x
                       + wy0 * pbt.x + wy1 * pbc.x + wy2 * pbb.x;
            float div2 = wx0 * pal.y + wx1 * pac.y + wx2 * par.y
                       + wy0 * pbt.y + wy1 * pbc.y + wy2 * pbb.y;
            float nu1 = v1 + theta * div1;
            float nu2 = v2 + theta * div2;
            if (!inb[s]) { nu1 = 0.f; nu2 = 0.f; }   // zero-padding semantics
            float2 nuv = make_float2(nu1, nu2);
            ruv[s] = nuv; su[idx] = nuv;
        }
        __syncthreads();
        if (phase == 2 && k == 5) break;   // 20th p-update is dead code

        // p-phase over li,lj in [k, REG-1-2k]  (valid cone of p^k)
        const int hi_p = REG - 1 - 2 * k;
        #pragma unroll
        for (int s = 0; s < SLOTS; ++s) {
            int idx = tid + s * TPB;
            int li = lis[s], lj = ljs[s];
            if (li < lo || li > hi_p || lj < lo || lj > hi_p) continue;
            float2 uc = ruv[s];
            float2 uR = su[idx + 1];
            float2 uB = su[idx + REG];
            float gu1x = uR.x - uc.x, gu1y = uB.x - uc.x;
            float gu2x = uR.y - uc.y, gu2y = uB.y - uc.y;
            float d1 = 1.f + r * (fabsf(gu1x) + fabsf(gu1y));
            float id1 = __builtin_amdgcn_rcpf(d1);
            float np11 = (rpa[s].x + r * gu1x) * id1;
            float np12 = (rpb[s].x + r * gu1y) * id1;
            float d2 = 1.f + r * (fabsf(gu2x) + fabsf(gu2y));
            float id2 = __builtin_amdgcn_rcpf(d2);
            float np21 = (rpa[s].y + r * gu2x) * id2;
            float np22 = (rpb[s].y + r * gu2y) * id2;
            if (!inb[s]) { np11 = 0.f; np12 = 0.f; np21 = 0.f; np22 = 0.f; }
            float2 npa = make_float2(np11, np21);
            float2 npb = make_float2(np12, np22);
            rpa[s] = npa; rpb[s] = npb;
            spa[idx] = npa; spb[idx] = npb;
        }
        __syncthreads();
    }

    // ---- epilogue --------------------------------------------------------
    if (phase != 2) {
        // write back interior [0,31]^2 (li,lj in [6,37]) from mirrors
        #pragma unroll
        for (int s = 0; s < SLOTS; ++s) {
            int li = lis[s], lj = ljs[s];
            if (li < HALO_L || li >= HALO_L + T || lj < HALO_L || lj >= HALO_L + T) continue;
            int gl = gofs[s];
            ug[gbase + gl] = ruv[s];
            pg[gbase + gl] = make_float4(rpa[s].x, rpa[s].y, rpb[s].x, rpb[s].y);
        }
    } else {
        // fused avgpool(3,1,1, /9 always); u^5 valid on [-1,32] — exact fit
        const float inv9 = 1.f / 9.f;
        #pragma unroll
        for (int s = 0; s < SLOTS; ++s) {
            int idx = tid + s * TPB;
            int li = lis[s], lj = ljs[s];
            if (li < HALO_L || li >= HALO_L + T || lj < HALO_L || lj >= HALO_L + T) continue;
            float2 a0 = su[idx - REG - 1], a1 = su[idx - REG], a2 = su[idx - REG + 1];
            float2 b0 = su[idx - 1],       b1 = su[idx],       b2 = su[idx + 1];
            float2 c0 = su[idx + REG - 1], c1 = su[idx + REG], c2 = su[idx + REG + 1];
            float s1 = a0.x + a1.x + a2.x + b0.x + b1.x + b2.x + c0.x + c1.x + c2.x;
            float s2 = a0.y + a1.y + a2.y + b0.y + b1.y + b2.y + c0.y + c1.y + c2.y;
            int gl = gofs[s];
            out[(size_t)bimg * 2 * HW + gl]      = s1 * inv9;
            out[(size_t)bimg * 2 * HW + HW + gl] = s2 * inv9;
        }
    }
}

// --------------------------------------------------------------- launch ---
extern "C" void kernel_launch(void* const* d_in, const int* in_sizes, int n_in,
                              void* d_out, int out_size, void* d_ws, size_t ws_size,
                              hipStream_t stream) {
    const float* x     = (const float*)d_in[0];
    const float* lam   = (const float*)d_in[1];
    const float* tau   = (const float*)d_in[2];
    const float* theta = (const float*)d_in[3];
    const float* wx    = (const float*)d_in[4];
    const float* wy    = (const float*)d_in[5];
    float* out = (float*)d_out;

    float*  ws = (float*)d_ws;
    float2* ug = (float2*)ws;                         // 8 MB
    float4* pg = (float4*)(ws + (size_t)2 * NTOT);    // 16 MB
    float2* st = (float2*)(ws + (size_t)6 * NTOT);    // 8 MB statics (gx,gy)

    k_statics<<<dim3(NTOT / 256), dim3(256), 0, stream>>>(x, st);
    for (int c = 0; c < 4; ++c) {
        int phase = (c == 0) ? 0 : (c == 3) ? 2 : 1;
        k_fused<<<dim3(NBLK), dim3(TPB), 0, stream>>>(
            x, ug, pg, st, lam, tau, theta, wx, wy, out, phase);
    }
}